// Round 1
// baseline (121.139 us; speedup 1.0000x reference)
//
#include <hip/hip_runtime.h>

// Problem constants (x: [3, 64, 64] float32)
#define C_DIM   3
#define H_DIM   64
#define W_DIM   64
#define HW      (H_DIM * W_DIM)          // 4096
#define N_TOT   (C_DIM * HW)             // 12288
#define NTHREADS 1024
#define PER     (N_TOT / NTHREADS)       // 12
#define EPS_F   0.1f

// Single-block kernel: compute center/err, block-wide inclusive scan of the
// mask for 1-based row indices, scatter nonzeros, write row 0 and terms.
__global__ __launch_bounds__(NTHREADS) void zono_scatter(
        const float* __restrict__ x,
        float* __restrict__ zono,     // (1+N) x N, already zeroed
        float* __restrict__ terms)    // N x 2, stored as float32 values
{
    const int tid  = threadIdx.x;
    const int base = tid * PER;

    float cen[PER];
    float ev[PER];
    bool  m[PER];
    int   cnt = 0;

#pragma unroll
    for (int i = 0; i < PER; ++i) {
        float xv = x[base + i];
        float a  = fmaxf(EPS_F - xv, 0.0f) * 0.5f;
        float b  = fmaxf(xv - (1.0f - EPS_F), 0.0f) * 0.5f;
        cen[i]   = xv + a - b;
        float e  = EPS_F - a - b;
        ev[i]    = e;
        m[i]     = (e >= 0.0f);
        cnt     += m[i] ? 1 : 0;
    }

    // Block-wide inclusive scan (Hillis-Steele) over per-thread mask counts.
    __shared__ int sh[NTHREADS];
    sh[tid] = cnt;
    __syncthreads();
    for (int off = 1; off < NTHREADS; off <<= 1) {
        int t = (tid >= off) ? sh[tid - off] : 0;
        __syncthreads();
        sh[tid] += t;
        __syncthreads();
    }
    // exclusive prefix of masked elements strictly before this thread's chunk
    int run = sh[tid] - cnt;

#pragma unroll
    for (int i = 0; i < PER; ++i) {
        const int idx = base + i;
        // row 0: center
        zono[idx] = cen[i];
        float rowf, fidxf;
        if (m[i]) {
            ++run;                              // 1-based cumsum value
            zono[(size_t)run * N_TOT + idx] = ev[i];
            rowf  = (float)run;
            fidxf = (float)(idx / HW);
        } else {
            rowf  = -1.0f;
            fidxf = -1.0f;
        }
        terms[2 * idx + 0] = rowf;
        terms[2 * idx + 1] = fidxf;
    }
}

extern "C" void kernel_launch(void* const* d_in, const int* in_sizes, int n_in,
                              void* d_out, int out_size, void* d_ws, size_t ws_size,
                              hipStream_t stream) {
    const float* x = (const float*)d_in[0];
    float* out = (float*)d_out;

    const size_t zono_elems = (size_t)(N_TOT + 1) * (size_t)N_TOT;  // 151,007,232

    // Zero the zonotope matrix (dominant cost: ~604 MB write).
    // Memset nodes are legal under graph capture.
    hipMemsetAsync(out, 0, zono_elems * sizeof(float), stream);

    // Compute + scatter + terms in one tiny single-block kernel.
    zono_scatter<<<1, NTHREADS, 0, stream>>>(x, out, out + zono_elems);
}